// Round 11
// baseline (197.650 us; speedup 1.0000x reference)
//
#include <hip/hip_runtime.h>
#include <stdint.h>

// ---------------------------------------------------------------------------
// MultiheadMaskedAttention (B=2, S=2048, H=1024, 16 heads x d=64)
// R20: R18 + lag-1 PV in attn (R14's idea, retried on top of R16's
// counted-vmcnt pipeline where its mechanism is now live):
//   iteration t: [barrier] -> read V(t-1) frags -> issue K(t+2),V(t+1)
//   -> QK(t) -> PV(t-1) (saved paS/pbS) -> exp2/pack -> save -> vmcnt(4).
//   The V-wait leaves the critical path (slack = full iteration; V dist
//   1 -> effective 2 with NO extra LDS); QK and PV are independent MFMA
//   streams overlapping the exp2/VALU chain.
//   Safety: V(t-1) ds_read issues BEFORE the V(t+1) stage that overwrites
//   the same 2-deep buffer (program order + sched_barrier); gload_lds
//   write-back lands >=~300cyc after issue vs ~15cyc ds_read -> safe for
//   all waves (all past the same barrier). Tail drains pending PV; the
//   end-of-iteration vmcnt(4) proves K(t+1),V(t) exactly as R16.
// GEMMs/prep identical to R18 (harness-verified; swizzle kept).
// ---------------------------------------------------------------------------

typedef __bf16 bf16;
typedef __attribute__((ext_vector_type(8))) __bf16 bf16x8;
typedef __attribute__((ext_vector_type(4))) __bf16 bf16x4;
typedef __attribute__((ext_vector_type(4))) float floatx4;
typedef __attribute__((ext_vector_type(16))) float floatx16;
typedef __attribute__((ext_vector_type(4))) unsigned int uint4v;
typedef __attribute__((ext_vector_type(2))) unsigned int uint2v;

#define SCL 0.18033688011112042f  // (1/sqrt(64)) * log2(e)

__device__ __forceinline__ floatx4 mfma_bf16(bf16x8 a, bf16x8 b, floatx4 c) {
  return __builtin_amdgcn_mfma_f32_16x16x32_bf16(a, b, c, 0, 0, 0);
}

// 32x32x16: A lane l holds m=l&31, k=(l>>5)*8+j ; B: n=l&31, k=(l>>5)*8+j ;
// D: n=lane&31, m=(reg&3)+8*(reg>>2)+4*(lane>>5)  [verified m74/m101, R12]
__device__ __forceinline__ floatx16 mfma32(bf16x8 a, bf16x8 b, floatx16 c) {
  return __builtin_amdgcn_mfma_f32_32x32x16_bf16(a, b, c, 0, 0, 0);
}

__device__ __forceinline__ void cp_g2l_16(const bf16* g, bf16* l) {
  // async global->LDS, 16B/lane; LDS dest = wave-uniform base + lane*16
  __builtin_amdgcn_global_load_lds(
      (const __attribute__((address_space(1))) void*)g,
      (__attribute__((address_space(3))) void*)l, 16, 0, 0);
}

__device__ __forceinline__ floatx16 zero16() {
  floatx16 z;
#pragma unroll
  for (int i = 0; i < 16; ++i) z[i] = 0.f;
  return z;
}

// two f32 -> one u32 of 2 bf16 (compiler emits cvt_pk; don't hand-write, m240)
__device__ __forceinline__ uint32_t pack2(float lo, float hi2) {
  union { bf16 h[2]; uint32_t u; } x;
  x.h[0] = (bf16)lo; x.h[1] = (bf16)hi2;
  return x.u;
}

// new_a = {a_lo, b_lo}, new_b = {a_hi, b_hi} across the lane<32 / lane>=32 halves
__device__ __forceinline__ uint2v permswap(uint32_t a, uint32_t b) {
  return __builtin_amdgcn_permlane32_swap(a, b, false, false);
}

__device__ __forceinline__ bf16x8 mk_pf(uint32_t w0, uint32_t w1, uint32_t w2,
                                        uint32_t w3) {
  union { uint4v u; bf16x8 v; } c;
  c.u = (uint4v){w0, w1, w2, w3};
  return c.v;
}

// ---- merged prep: cast x -> bf16 ; cast+transpose w_qkv, w_o ----
__global__ __launch_bounds__(256) void prep_kernel(
    const float* __restrict__ x, bf16* __restrict__ xb,
    const float* __restrict__ w_qkv, bf16* __restrict__ wqkvt,
    const float* __restrict__ w_o, bf16* __restrict__ wot) {
  const int b = blockIdx.x;
  const int tid = threadIdx.x;
  if (b < 4096) {
    const int i = (b * 256 + tid) * 4;
    floatx4 v = *(const floatx4*)(x + i);
    bf16x4 o;
    o[0] = (bf16)v[0]; o[1] = (bf16)v[1]; o[2] = (bf16)v[2]; o[3] = (bf16)v[3];
    *(bf16x4*)(xb + i) = o;
    return;
  }
  __shared__ float tile[32][33];
  const float* W; bf16* Wt; int K, N, n0, k0;
  if (b < 7168) {
    const int bb = b - 4096;
    W = w_qkv; Wt = wqkvt; K = 1024; N = 3072;
    n0 = (bb % 96) * 32; k0 = (bb / 96) * 32;
  } else {
    const int bb = b - 7168;
    W = w_o; Wt = wot; K = 1024; N = 1024;
    n0 = (bb & 31) * 32; k0 = (bb >> 5) * 32;
  }
  const int tx = tid & 31, ty = tid >> 5;
  for (int i = 0; i < 4; ++i)
    tile[ty + 8 * i][tx] = W[(size_t)(k0 + ty + 8 * i) * N + n0 + tx];
  __syncthreads();
  for (int i = 0; i < 4; ++i)
    Wt[(size_t)(n0 + ty + 8 * i) * K + k0 + tx] = (bf16)tile[tx][ty + 8 * i];
}

// ---- GEMM: C = A(M x K bf16 rm) * Bt(N x K bf16 rm)^T + bias ----
// R18 (verified): 2-barrier structure + 4-slot XOR-swizzled As/Bs slots.
template <int MODE, int MI>
__global__ __launch_bounds__(256, 3) void gemm_bt_kernel(
    const bf16* __restrict__ A, const bf16* __restrict__ Bt,
    const float* __restrict__ bias, float* __restrict__ outF,
    bf16* __restrict__ qb, bf16* __restrict__ kb, bf16* __restrict__ vtb,
    int N, int K) {
  constexpr int BM = MI * 32;
  __shared__ bf16 As[BM * 32];
  __shared__ bf16 Bs[128 * 32];
  const int tid = threadIdx.x;
  const int w = tid >> 6, lane = tid & 63;
  const int l16 = lane & 15, quad = lane >> 4;
  const int m0 = blockIdx.y * BM, n0 = blockIdx.x * 128;
  const int wm = (w & 1) * (BM / 2), wn = (w >> 1) * 64;

  // staging thread (r,c): dest = physical slot c of row r (linear in lane);
  // source = logical chunk jj = (c - r - (r>>2)) & 3 of that row.
  const int r4 = lane >> 2, c4 = lane & 3;
  const int jj = (c4 - r4 - (r4 >> 2)) & 3;
  const int arow = w * (BM / 4) + r4;
  const bf16* Ag = A + (size_t)(m0 + arow) * K + jj * 8;
  bf16* Al = As + arow * 32 + c4 * 8;
  const int brow = w * 32 + r4;
  const bf16* Bg = Bt + (size_t)(n0 + brow) * K + jj * 8;
  bf16* Bl = Bs + brow * 32 + c4 * 8;

  floatx4 acc[MI][4];
#pragma unroll
  for (int i = 0; i < MI; ++i)
#pragma unroll
    for (int j = 0; j < 4; ++j) acc[i][j] = (floatx4){0.f, 0.f, 0.f, 0.f};

  for (int k0 = 0; k0 < K; k0 += 32) {
    __syncthreads();
    cp_g2l_16(Ag + k0, Al);
    if (MI == 4) cp_g2l_16(Ag + (size_t)16 * K + k0, Al + 16 * 32);
    cp_g2l_16(Bg + k0, Bl);
    cp_g2l_16(Bg + (size_t)16 * K + k0, Bl + 16 * 32);
    __syncthreads();
    bf16x8 af[MI], bfr[4];
#pragma unroll
    for (int i = 0; i < MI; ++i) {
      const int R = wm + i * 16 + l16;
      af[i] = *(const bf16x8*)(&As[R * 32 + ((quad + R + (R >> 2)) & 3) * 8]);
    }
#pragma unroll
    for (int j = 0; j < 4; ++j) {
      const int Rb = wn + j * 16 + l16;
      bfr[j] = *(const bf16x8*)(&Bs[Rb * 32 + ((quad + Rb + (Rb >> 2)) & 3) * 8]);
    }
#pragma unroll
    for (int i = 0; i < MI; ++i)
#pragma unroll
      for (int j = 0; j < 4; ++j)
        acc[i][j] = mfma_bf16(af[i], bfr[j], acc[i][j]);
  }

#pragma unroll
  for (int i = 0; i < MI; ++i)
#pragma unroll
    for (int j = 0; j < 4; ++j) {
      const int nn = n0 + wn + j * 16 + l16;
      const float bv = bias[nn];
      const int mbase = m0 + wm + i * 16 + quad * 4;
      if (MODE == 1) {
#pragma unroll
        for (int r = 0; r < 4; ++r)
          outF[(size_t)(mbase + r) * N + nn] = acc[i][j][r] + bv;
      } else {
        const int which = nn >> 10;  // uniform per block
        const int rem = nn & 1023;
        const int h = rem >> 6, d = rem & 63;
        const int b = mbase >> 11, s = mbase & 2047;
        const size_t bh = (size_t)(b * 16 + h);
        if (which == 2) {
          bf16x4 pk;
#pragma unroll
          for (int r = 0; r < 4; ++r) pk[r] = (bf16)(acc[i][j][r] + bv);
          *(bf16x4*)(vtb + (bh * 64 + d) * 2048 + s) = pk;
        } else if (which == 0) {
#pragma unroll
          for (int r = 0; r < 4; ++r)
            qb[(bh * 2048 + s + r) * 64 + d] = (bf16)((acc[i][j][r] + bv) * SCL);
        } else {
#pragma unroll
          for (int r = 0; r < 4; ++r)
            kb[(bh * 2048 + s + r) * 64 + d] = (bf16)(acc[i][j][r] + bv);
        }
      }
    }
}

// ---- Flash attention, causal. 1024 blocks x 256 threads (4 waves). ------
// R20: R16/R18 counted-vmcnt pipeline + lag-1 PV.
__global__ __launch_bounds__(256, 4) void attn_kernel(
    const bf16* __restrict__ Qb, const bf16* __restrict__ Kb,
    const bf16* __restrict__ Vtb, bf16* __restrict__ attnb) {
  __shared__ bf16 Ks[3][4096];  // [buf][64 s-rows x 64 d] swizzled chunks
  __shared__ bf16 Vs[2][4096];  // [buf][64 d-rows x 64 s] swizzled chunks
  const int bid = blockIdx.x;
  const int c = bid & 255, qq = bid >> 8;
  const int bh = c & 31;        // head: all 32 blocks of a head on one XCD
  const int kk = c >> 5;        // 0..7
  // stride-256 columns get groups {k, 31-k, 8+k, 23-k}: 66 iters/column
  const int g = (qq == 0) ? kk : (qq == 1) ? 31 - kk
              : (qq == 2) ? 8 + kk : 23 - kk;
  const int tid = threadIdx.x;
  const int w = tid >> 6, lane = tid & 63;
  const int l31 = lane & 31, hi = lane >> 5;
  const int strip = w >> 1, ms = w & 1;
  const int q0s = g * 64 + strip * 32;  // this wave's 32 q-rows
  const int b = bh >> 4, h = bh & 15;
  const int nt = g + 1;

  const bf16* Qh = Qb + (size_t)bh * 2048 * 64;
  const bf16* Kh = Kb + (size_t)bh * 2048 * 64;
  const bf16* Vh = Vtb + (size_t)bh * 64 * 2048;

  // staging: thread stages chunks {tid, tid+256} of K and of V (16B each).
  // dest chunk c: row=c>>3, slot=c&7 holds source chunk (slot-row)&7
  const int c0 = tid, c1 = tid + 256;
  const int kof0 = (c0 >> 3) * 64 + ((((c0 & 7) - (c0 >> 3)) & 7) * 8);
  const int kof1 = (c1 >> 3) * 64 + ((((c1 & 7) - (c1 >> 3)) & 7) * 8);
  const int vof0 = (c0 >> 3) * 2048 + ((((c0 & 7) - (c0 >> 3)) & 7) * 8);
  const int vof1 = (c1 >> 3) * 2048 + ((((c1 & 7) - (c1 >> 3)) & 7) * 8);

  // Q B-frags: n=q=q0s+l31, k=d=kd*16+hi*8+j
  bf16x8 qf[4];
  {
    const bf16* Qr = Qh + (size_t)(q0s + l31) * 64 + hi * 8;
#pragma unroll
    for (int kd = 0; kd < 4; ++kd) qf[kd] = *(const bf16x8*)(Qr + kd * 16);
  }
  bf16x8 ones;
#pragma unroll
  for (int j = 0; j < 8; ++j) ones[j] = (bf16)1.0f;

  floatx16 O0 = zero16(), O1 = zero16(), Ol = zero16();

  // prologue: K(0)->Kb0, K(1 or clamp)->Kb1, V(0)->Vb0 ; keep K1,V0 in flight
  {
    const int k1 = (1 < nt) ? 1 : 0;
    cp_g2l_16(Kh + kof0, &Ks[0][c0 * 8]);
    cp_g2l_16(Kh + kof1, &Ks[0][c1 * 8]);
    cp_g2l_16(Kh + (size_t)k1 * 4096 + kof0, &Ks[1][c0 * 8]);
    cp_g2l_16(Kh + (size_t)k1 * 4096 + kof1, &Ks[1][c1 * 8]);
    cp_g2l_16(Vh + vof0, &Vs[0][c0 * 8]);
    cp_g2l_16(Vh + vof1, &Vs[0][c1 * 8]);
    asm volatile("s_waitcnt vmcnt(4)" ::: "memory");  // K(0) staged
    __builtin_amdgcn_sched_barrier(0);
  }

  const int ksA = ms * 2, ksB = ms * 2 + 1;  // this wave's two 16-s slots
  const int r0v = l31, r1v = 32 + l31;
  bf16x8 paS, pbS;  // saved P A-frags for PV(t-1)
  int havePrev = 0;
  int kr = 0;  // K read buffer = t % 3
  for (int t = 0; t < nt; ++t) {
    // all waves: K(t),V(t-1) visible (proven by end-of-(t-1) vmcnt(4)).
    __builtin_amdgcn_s_barrier();
    __builtin_amdgcn_sched_barrier(0);

    // (a) V(t-1) fragments — MUST issue before the V(t+1) stage below
    // overwrites Vs[(t-1)&1]. ds_read completes ~15cyc; gload_lds write-back
    // lands >=~300cyc after issue; all waves are past the same barrier.
    bf16x8 va0, va1, vb0, vb1;
    if (havePrev) {
      const bf16* VsP = &Vs[(t - 1) & 1][0];
      va0 = *(const bf16x8*)(&VsP[r0v * 64 + (((ksA * 2 + hi) + r0v) & 7) * 8]);
      va1 = *(const bf16x8*)(&VsP[r1v * 64 + (((ksA * 2 + hi) + r1v) & 7) * 8]);
      vb0 = *(const bf16x8*)(&VsP[r0v * 64 + (((ksB * 2 + hi) + r0v) & 7) * 8]);
      vb1 = *(const bf16x8*)(&VsP[r1v * 64 + (((ksB * 2 + hi) + r1v) & 7) * 8]);
    }
    __builtin_amdgcn_sched_barrier(0);  // pin reads before staging issue

    // (b) issue staging: K(t+2)->Kb[(t+2)%3], V(t+1)->Vb[(t+1)&1].
    // Tail: clamped source (tile 0) into the (dead) dest keeps vmcnt uniform.
    {
      const int tk = (t + 2 < nt) ? t + 2 : 0;
      const int tv = (t + 1 < nt) ? t + 1 : 0;
      const int kst = (kr >= 1) ? kr - 1 : 2;  // (t+2)%3
      cp_g2l_16(Kh + (size_t)tk * 4096 + kof0, &Ks[kst][c0 * 8]);
      cp_g2l_16(Kh + (size_t)tk * 4096 + kof1, &Ks[kst][c1 * 8]);
      cp_g2l_16(Vh + (size_t)tv * 64 + vof0, &Vs[(t + 1) & 1][c0 * 8]);
      cp_g2l_16(Vh + (size_t)tv * 64 + vof1, &Vs[(t + 1) & 1][c1 * 8]);
    }

    const bool diag = (t == g);
    const bool skip = diag && strip == 0 && ms == 1;  // fully-masked half

    // (c) QK(t): 4 chained MFMAs over d
    floatx16 sf;
    if (!skip) {
      sf = zero16();
      const bf16* KsC = &Ks[kr][0];
      const int row = ms * 32 + l31;
      __builtin_amdgcn_s_setprio(1);
#pragma unroll
      for (int kd = 0; kd < 4; ++kd) {
        bf16x8 kf = *(const bf16x8*)(
            &KsC[row * 64 + (((kd * 2 + hi) + row) & 7) * 8]);
        sf = mfma32(kf, qf[kd], sf);
      }
      __builtin_amdgcn_s_setprio(0);
    }

    // (d) PV(t-1): independent MFMA stream, overlaps QK latency + softmax
    if (havePrev) {
      __builtin_amdgcn_s_setprio(1);
      O0 = mfma32(paS, va0, O0);
      O1 = mfma32(paS, va1, O1);
      Ol = mfma32(paS, ones, Ol);
      O0 = mfma32(pbS, vb0, O0);
      O1 = mfma32(pbS, vb1, O1);
      Ol = mfma32(pbS, ones, Ol);
      __builtin_amdgcn_s_setprio(0);
    }

    // (e) softmax(t): mask -> exp2 -> pack -> permlane swap -> save P frags
    if (!skip) {
      float e[16];
#pragma unroll
      for (int r = 0; r < 16; ++r) {
        float s = sf[r];
        if (diag) {
          const int kc = t * 64 + ms * 32 + (r & 3) + 8 * (r >> 2) + 4 * hi;
          s = (kc <= q0s + l31) ? s : -1e30f;
        }
        e[r] = __builtin_amdgcn_exp2f(s);
      }
      uint32_t W[8];
#pragma unroll
      for (int i = 0; i < 8; ++i) W[i] = pack2(e[2 * i], e[2 * i + 1]);
      uint2v s0 = permswap(W[0], W[2]);
      uint2v s1 = permswap(W[1], W[3]);
      paS = mk_pf(s0.x, s1.x, s0.y, s1.y);
      uint2v s2 = permswap(W[4], W[6]);
      uint2v s3 = permswap(W[5], W[7]);
      pbS = mk_pf(s2.x, s3.x, s2.y, s3.y);
      havePrev = 1;
    } else {
      havePrev = 0;
    }

    // (f) end-of-iteration: drain K(t+1),V(t); leave K(t+2),V(t+1) in flight.
    // Nothing in THIS iteration depends on it -> full-iteration slack.
    asm volatile("s_waitcnt vmcnt(4)" ::: "memory");
    __builtin_amdgcn_sched_barrier(0);
    kr = (kr == 2) ? 0 : kr + 1;
  }

  // tail: drain pending PV(nt-1). V(nt-1) in Vs[(nt-1)&1]; the dummy V(nt)
  // stage went to the OTHER buffer; proven by the last vmcnt(4).
  if (havePrev) {
    const bf16* VsP = &Vs[(nt - 1) & 1][0];
    bf16x8 va0 = *(const bf16x8*)(&VsP[r0v * 64 + (((ksA * 2 + hi) + r0v) & 7) * 8]);
    bf16x8 va1 = *(const bf16x8*)(&VsP[r1v * 64 + (((ksA * 2 + hi) + r1v) & 7) * 8]);
    bf16x8 vb0 = *(const bf16x8*)(&VsP[r0v * 64 + (((ksB * 2 + hi) + r0v) & 7) * 8]);
    bf16x8 vb1 = *(const bf16x8*)(&VsP[r1v * 64 + (((ksB * 2 + hi) + r1v) & 7) * 8]);
    O0 = mfma32(paS, va0, O0);
    O1 = mfma32(paS, va1, O1);
    Ol = mfma32(paS, ones, Ol);
    O0 = mfma32(pbS, vb0, O0);
    O1 = mfma32(pbS, vb1, O1);
    Ol = mfma32(pbS, ones, Ol);
  }

  // merge ms halves (R13-verified layout): full drain once, reuse LDS.
  __syncthreads();
  float* fO = (float*)(&Ks[0][0]);  // [strip][ql][d] = 4096 floats (16KB)
  float* fL = (float*)(&Vs[0][0]);  // [strip][ql] = 64 floats
  if (ms == 1) {
#pragma unroll
    for (int r = 0; r < 16; ++r) {
      const int ql = (r & 3) + 8 * (r >> 2) + 4 * hi;
      fO[strip * 2048 + ql * 64 + l31] = O0[r];
      fO[strip * 2048 + ql * 64 + 32 + l31] = O1[r];
      if (l31 == 0) fL[strip * 32 + ql] = Ol[r];
    }
  }
  __syncthreads();
  if (ms == 0) {
#pragma unroll
    for (int r = 0; r < 16; ++r) {
      const int ql = (r & 3) + 8 * (r >> 2) + 4 * hi;
      const float o0 = O0[r] + fO[strip * 2048 + ql * 64 + l31];
      const float o1 = O1[r] + fO[strip * 2048 + ql * 64 + 32 + l31];
      const float inv = 1.f / (Ol[r] + fL[strip * 32 + ql]);
      bf16* dst = attnb + ((size_t)(b * 2048 + q0s + ql)) * 1024 + h * 64;
      dst[l31] = (bf16)(o0 * inv);
      dst[32 + l31] = (bf16)(o1 * inv);
    }
  }
}

// ---------------------------------------------------------------------------
extern "C" void kernel_launch(void* const* d_in, const int* in_sizes, int n_in,
                              void* d_out, int out_size, void* d_ws, size_t ws_size,
                              hipStream_t stream) {
  const float* x     = (const float*)d_in[0];  // (2,2048,1024)
  const float* w_qkv = (const float*)d_in[1];  // (1024,3072)
  const float* b_qkv = (const float*)d_in[2];  // (3072)
  const float* w_o   = (const float*)d_in[3];  // (1024,1024)
  const float* b_o   = (const float*)d_in[4];  // (1024)
  float* out = (float*)d_out;                  // (2,2048,1024) fp32

  char* ws = (char*)d_ws;
  bf16* xb    = (bf16*)ws; ws += (size_t)4096 * 1024 * 2;
  bf16* wqkvt = (bf16*)ws; ws += (size_t)3072 * 1024 * 2;
  bf16* wot   = (bf16*)ws; ws += (size_t)1024 * 1024 * 2;
  bf16* qb    = (bf16*)ws; ws += (size_t)32 * 2048 * 64 * 2;
  bf16* kb    = (bf16*)ws; ws += (size_t)32 * 2048 * 64 * 2;
  bf16* vtb   = (bf16*)ws; ws += (size_t)32 * 2048 * 64 * 2;  // (bh,64,S)
  bf16* attnb = (bf16*)ws; ws += (size_t)4096 * 1024 * 2;

  prep_kernel<<<8192, 256, 0, stream>>>(x, xb, w_qkv, wqkvt, w_o, wot);
  gemm_bt_kernel<0, 4><<<dim3(24, 32), 256, 0, stream>>>(
      xb, wqkvt, b_qkv, nullptr, qb, kb, vtb, 3072, 1024);
  attn_kernel<<<1024, 256, 0, stream>>>(qb, kb, vtb, attnb);
  gemm_bt_kernel<1, 2><<<dim3(8, 64), 256, 0, stream>>>(
      attnb, wot, b_o, out, nullptr, nullptr, nullptr, 1024, 1024);
}

// Round 12
// 166.966 us; speedup vs baseline: 1.1838x; 1.1838x over previous
//
#include <hip/hip_runtime.h>
#include <stdint.h>

// ---------------------------------------------------------------------------
// MultiheadMaskedAttention (B=2, S=2048, H=1024, 16 heads x d=64)
// R21: attn reverted to R16 (harness-verified best; R20's lag-PV regressed
// 37->65us — second failed attn restructure, attn is now frozen).
// GEMMs: BK 32->64. Halves the per-K-step vmcnt(0)+barrier drain count
// (32->16 steps, the m97 ~20% stall), doubles MFMA per drain. LDS stays
// small (MI=4: 32KB, MI=2: 24KB) so occupancy remains grid-limited 3/CU
// (m132's BK=128 failure mode avoided). Staging + fragment-read swizzle is
// the attn K-tile pattern verbatim (slot=(c&7), src jj=((c&7)-(c>>3))&7,
// read slot=(kq*4+quad+R)&7) — verified in-harness since R13. Epilogue and
// 2-barrier structure unchanged. prep unchanged.
// ---------------------------------------------------------------------------

typedef __bf16 bf16;
typedef __attribute__((ext_vector_type(8))) __bf16 bf16x8;
typedef __attribute__((ext_vector_type(4))) __bf16 bf16x4;
typedef __attribute__((ext_vector_type(4))) float floatx4;
typedef __attribute__((ext_vector_type(16))) float floatx16;
typedef __attribute__((ext_vector_type(4))) unsigned int uint4v;
typedef __attribute__((ext_vector_type(2))) unsigned int uint2v;

#define SCL 0.18033688011112042f  // (1/sqrt(64)) * log2(e)

__device__ __forceinline__ floatx4 mfma_bf16(bf16x8 a, bf16x8 b, floatx4 c) {
  return __builtin_amdgcn_mfma_f32_16x16x32_bf16(a, b, c, 0, 0, 0);
}

// 32x32x16: A lane l holds m=l&31, k=(l>>5)*8+j ; B: n=l&31, k=(l>>5)*8+j ;
// D: n=lane&31, m=(reg&3)+8*(reg>>2)+4*(lane>>5)  [verified m74/m101, R12]
__device__ __forceinline__ floatx16 mfma32(bf16x8 a, bf16x8 b, floatx16 c) {
  return __builtin_amdgcn_mfma_f32_32x32x16_bf16(a, b, c, 0, 0, 0);
}

__device__ __forceinline__ void cp_g2l_16(const bf16* g, bf16* l) {
  // async global->LDS, 16B/lane; LDS dest = wave-uniform base + lane*16
  __builtin_amdgcn_global_load_lds(
      (const __attribute__((address_space(1))) void*)g,
      (__attribute__((address_space(3))) void*)l, 16, 0, 0);
}

__device__ __forceinline__ floatx16 zero16() {
  floatx16 z;
#pragma unroll
  for (int i = 0; i < 16; ++i) z[i] = 0.f;
  return z;
}

// two f32 -> one u32 of 2 bf16 (compiler emits cvt_pk; don't hand-write, m240)
__device__ __forceinline__ uint32_t pack2(float lo, float hi2) {
  union { bf16 h[2]; uint32_t u; } x;
  x.h[0] = (bf16)lo; x.h[1] = (bf16)hi2;
  return x.u;
}

// new_a = {a_lo, b_lo}, new_b = {a_hi, b_hi} across the lane<32 / lane>=32 halves
__device__ __forceinline__ uint2v permswap(uint32_t a, uint32_t b) {
  return __builtin_amdgcn_permlane32_swap(a, b, false, false);
}

__device__ __forceinline__ bf16x8 mk_pf(uint32_t w0, uint32_t w1, uint32_t w2,
                                        uint32_t w3) {
  union { uint4v u; bf16x8 v; } c;
  c.u = (uint4v){w0, w1, w2, w3};
  return c.v;
}

// ---- merged prep: cast x -> bf16 ; cast+transpose w_qkv, w_o ----
__global__ __launch_bounds__(256) void prep_kernel(
    const float* __restrict__ x, bf16* __restrict__ xb,
    const float* __restrict__ w_qkv, bf16* __restrict__ wqkvt,
    const float* __restrict__ w_o, bf16* __restrict__ wot) {
  const int b = blockIdx.x;
  const int tid = threadIdx.x;
  if (b < 4096) {
    const int i = (b * 256 + tid) * 4;
    floatx4 v = *(const floatx4*)(x + i);
    bf16x4 o;
    o[0] = (bf16)v[0]; o[1] = (bf16)v[1]; o[2] = (bf16)v[2]; o[3] = (bf16)v[3];
    *(bf16x4*)(xb + i) = o;
    return;
  }
  __shared__ float tile[32][33];
  const float* W; bf16* Wt; int K, N, n0, k0;
  if (b < 7168) {
    const int bb = b - 4096;
    W = w_qkv; Wt = wqkvt; K = 1024; N = 3072;
    n0 = (bb % 96) * 32; k0 = (bb / 96) * 32;
  } else {
    const int bb = b - 7168;
    W = w_o; Wt = wot; K = 1024; N = 1024;
    n0 = (bb & 31) * 32; k0 = (bb >> 5) * 32;
  }
  const int tx = tid & 31, ty = tid >> 5;
  for (int i = 0; i < 4; ++i)
    tile[ty + 8 * i][tx] = W[(size_t)(k0 + ty + 8 * i) * N + n0 + tx];
  __syncthreads();
  for (int i = 0; i < 4; ++i)
    Wt[(size_t)(n0 + ty + 8 * i) * K + k0 + tx] = (bf16)tile[tx][ty + 8 * i];
}

// ---- GEMM: C = A(M x K bf16 rm) * Bt(N x K bf16 rm)^T + bias ----
// R21: BK=64, 2-barrier structure, attn-style 8-slot staging swizzle.
template <int MODE, int MI>
__global__ __launch_bounds__(256, 3) void gemm_bt_kernel(
    const bf16* __restrict__ A, const bf16* __restrict__ Bt,
    const float* __restrict__ bias, float* __restrict__ outF,
    bf16* __restrict__ qb, bf16* __restrict__ kb, bf16* __restrict__ vtb,
    int N, int K) {
  constexpr int BM = MI * 32;
  __shared__ bf16 As[BM * 64];   // [BM rows][64 cols], 8-slot swizzled
  __shared__ bf16 Bs[128 * 64];
  const int tid = threadIdx.x;
  const int w = tid >> 6, lane = tid & 63;
  const int l16 = lane & 15, quad = lane >> 4;
  const int m0 = blockIdx.y * BM, n0 = blockIdx.x * 128;
  const int wm = (w & 1) * (BM / 2), wn = (w >> 1) * 64;

  // staging: chunk c (16B): row=c>>3, slot=c&7; LDS dest = c*8 elems
  // (linear); source = logical chunk jj=((c&7)-(c>>3))&7 of that row.
  // Thread handles chunks c = tid + 256*p.
  constexpr int ACH = (BM * 8) / 256;  // 4 (MI=4) or 2 (MI=2)
  const bf16* AgS[ACH];
  const bf16* BgS[4];
#pragma unroll
  for (int p = 0; p < ACH; ++p) {
    const int c = tid + 256 * p;
    AgS[p] = A + (size_t)(m0 + (c >> 3)) * K + ((((c & 7) - (c >> 3)) & 7) * 8);
  }
#pragma unroll
  for (int p = 0; p < 4; ++p) {
    const int c = tid + 256 * p;
    BgS[p] = Bt + (size_t)(n0 + (c >> 3)) * K + ((((c & 7) - (c >> 3)) & 7) * 8);
  }

  floatx4 acc[MI][4];
#pragma unroll
  for (int i = 0; i < MI; ++i)
#pragma unroll
    for (int j = 0; j < 4; ++j) acc[i][j] = (floatx4){0.f, 0.f, 0.f, 0.f};

  for (int k0 = 0; k0 < K; k0 += 64) {  // 16 steps (was 32)
    __syncthreads();
#pragma unroll
    for (int p = 0; p < ACH; ++p)
      cp_g2l_16(AgS[p] + k0, As + (tid + 256 * p) * 8);
#pragma unroll
    for (int p = 0; p < 4; ++p)
      cp_g2l_16(BgS[p] + k0, Bs + (tid + 256 * p) * 8);
    __syncthreads();

    // fragment reads: row R, logical chunk kq*4+quad -> slot (kq*4+quad+R)&7
    bf16x8 af[MI][2], bfr[4][2];
#pragma unroll
    for (int i = 0; i < MI; ++i) {
      const int R = wm + i * 16 + l16;
#pragma unroll
      for (int kq = 0; kq < 2; ++kq)
        af[i][kq] = *(const bf16x8*)(&As[R * 64 + ((kq * 4 + quad + R) & 7) * 8]);
    }
#pragma unroll
    for (int j = 0; j < 4; ++j) {
      const int Rb = wn + j * 16 + l16;
#pragma unroll
      for (int kq = 0; kq < 2; ++kq)
        bfr[j][kq] = *(const bf16x8*)(&Bs[Rb * 64 + ((kq * 4 + quad + Rb) & 7) * 8]);
    }
#pragma unroll
    for (int i = 0; i < MI; ++i)
#pragma unroll
      for (int j = 0; j < 4; ++j) {
        acc[i][j] = mfma_bf16(af[i][0], bfr[j][0], acc[i][j]);
        acc[i][j] = mfma_bf16(af[i][1], bfr[j][1], acc[i][j]);
      }
  }

#pragma unroll
  for (int i = 0; i < MI; ++i)
#pragma unroll
    for (int j = 0; j < 4; ++j) {
      const int nn = n0 + wn + j * 16 + l16;
      const float bv = bias[nn];
      const int mbase = m0 + wm + i * 16 + quad * 4;
      if (MODE == 1) {
#pragma unroll
        for (int r = 0; r < 4; ++r)
          outF[(size_t)(mbase + r) * N + nn] = acc[i][j][r] + bv;
      } else {
        const int which = nn >> 10;  // uniform per block
        const int rem = nn & 1023;
        const int h = rem >> 6, d = rem & 63;
        const int b = mbase >> 11, s = mbase & 2047;
        const size_t bh = (size_t)(b * 16 + h);
        if (which == 2) {
          bf16x4 pk;
#pragma unroll
          for (int r = 0; r < 4; ++r) pk[r] = (bf16)(acc[i][j][r] + bv);
          *(bf16x4*)(vtb + (bh * 64 + d) * 2048 + s) = pk;
        } else if (which == 0) {
#pragma unroll
          for (int r = 0; r < 4; ++r)
            qb[(bh * 2048 + s + r) * 64 + d] = (bf16)((acc[i][j][r] + bv) * SCL);
        } else {
#pragma unroll
          for (int r = 0; r < 4; ++r)
            kb[(bh * 2048 + s + r) * 64 + d] = (bf16)(acc[i][j][r] + bv);
        }
      }
    }
}

// ---- Flash attention, causal. 1024 blocks x 256 threads (4 waves). ------
// R16 structure (harness-verified): K 3-deep LDS (prefetch distance 2),
// V 2-deep (distance 1); raw s_barrier at loop top; mid-iteration vmcnt(4).
__global__ __launch_bounds__(256, 4) void attn_kernel(
    const bf16* __restrict__ Qb, const bf16* __restrict__ Kb,
    const bf16* __restrict__ Vtb, bf16* __restrict__ attnb) {
  __shared__ bf16 Ks[3][4096];  // [buf][64 s-rows x 64 d] swizzled chunks
  __shared__ bf16 Vs[2][4096];  // [buf][64 d-rows x 64 s] swizzled chunks
  const int bid = blockIdx.x;
  const int c = bid & 255, qq = bid >> 8;
  const int bh = c & 31;        // head: all 32 blocks of a head on one XCD
  const int kk = c >> 5;        // 0..7
  // stride-256 columns get groups {k, 31-k, 8+k, 23-k}: 66 iters/column
  const int g = (qq == 0) ? kk : (qq == 1) ? 31 - kk
              : (qq == 2) ? 8 + kk : 23 - kk;
  const int tid = threadIdx.x;
  const int w = tid >> 6, lane = tid & 63;
  const int l31 = lane & 31, hi = lane >> 5;
  const int strip = w >> 1, ms = w & 1;
  const int q0s = g * 64 + strip * 32;  // this wave's 32 q-rows
  const int b = bh >> 4, h = bh & 15;
  const int nt = g + 1;

  const bf16* Qh = Qb + (size_t)bh * 2048 * 64;
  const bf16* Kh = Kb + (size_t)bh * 2048 * 64;
  const bf16* Vh = Vtb + (size_t)bh * 64 * 2048;

  // staging: thread stages chunks {tid, tid+256} of K and of V (16B each).
  // dest chunk c: row=c>>3, slot=c&7 holds source chunk (slot-row)&7
  const int c0 = tid, c1 = tid + 256;
  const int kof0 = (c0 >> 3) * 64 + ((((c0 & 7) - (c0 >> 3)) & 7) * 8);
  const int kof1 = (c1 >> 3) * 64 + ((((c1 & 7) - (c1 >> 3)) & 7) * 8);
  const int vof0 = (c0 >> 3) * 2048 + ((((c0 & 7) - (c0 >> 3)) & 7) * 8);
  const int vof1 = (c1 >> 3) * 2048 + ((((c1 & 7) - (c1 >> 3)) & 7) * 8);

  // Q B-frags: n=q=q0s+l31, k=d=kd*16+hi*8+j
  bf16x8 qf[4];
  {
    const bf16* Qr = Qh + (size_t)(q0s + l31) * 64 + hi * 8;
#pragma unroll
    for (int kd = 0; kd < 4; ++kd) qf[kd] = *(const bf16x8*)(Qr + kd * 16);
  }
  bf16x8 ones;
#pragma unroll
  for (int j = 0; j < 8; ++j) ones[j] = (bf16)1.0f;

  floatx16 O0 = zero16(), O1 = zero16(), Ol = zero16();

  // prologue: K(0)->Kb0, K(1 or clamp)->Kb1, V(0)->Vb0 ; keep K1,V0 in flight
  {
    const int k1 = (1 < nt) ? 1 : 0;
    cp_g2l_16(Kh + kof0, &Ks[0][c0 * 8]);
    cp_g2l_16(Kh + kof1, &Ks[0][c1 * 8]);
    cp_g2l_16(Kh + (size_t)k1 * 4096 + kof0, &Ks[1][c0 * 8]);
    cp_g2l_16(Kh + (size_t)k1 * 4096 + kof1, &Ks[1][c1 * 8]);
    cp_g2l_16(Vh + vof0, &Vs[0][c0 * 8]);
    cp_g2l_16(Vh + vof1, &Vs[0][c1 * 8]);
    asm volatile("s_waitcnt vmcnt(4)" ::: "memory");  // K(0) staged
    __builtin_amdgcn_sched_barrier(0);
  }

  int kr = 0;  // K read buffer = t % 3
  for (int t = 0; t < nt; ++t) {
    // all waves: K(t) visible (issuer drained at its mid-(t-1) vmcnt(4));
    // buffers being overwritten below were fully read during t-1.
    __builtin_amdgcn_s_barrier();
    __builtin_amdgcn_sched_barrier(0);

    // issue staging: K(t+2)->Kb[(t+2)%3], V(t+1)->Vb[(t+1)&1].
    // Tail: clamped source (tile 0) into the (dead) dest keeps vmcnt uniform.
    {
      const int tk = (t + 2 < nt) ? t + 2 : 0;
      const int tv = (t + 1 < nt) ? t + 1 : 0;
      const int kst = (kr >= 1) ? kr - 1 : 2;  // (t+2)%3
      cp_g2l_16(Kh + (size_t)tk * 4096 + kof0, &Ks[kst][c0 * 8]);
      cp_g2l_16(Kh + (size_t)tk * 4096 + kof1, &Ks[kst][c1 * 8]);
      cp_g2l_16(Vh + (size_t)tv * 64 + vof0, &Vs[(t + 1) & 1][c0 * 8]);
      cp_g2l_16(Vh + (size_t)tv * 64 + vof1, &Vs[(t + 1) & 1][c1 * 8]);
    }

    const bool diag = (t == g);
    if (!(diag && strip == 0 && ms == 1)) {  // skip fully-masked half-tile
      const bf16* KsC = &Ks[kr][0];

      // S^T = K*Q^T over this wave's 32 s-rows: 4 chained MFMAs over d
      floatx16 sf = zero16();
      const int row = ms * 32 + l31;
      __builtin_amdgcn_s_setprio(1);
#pragma unroll
      for (int kd = 0; kd < 4; ++kd) {
        bf16x8 kf = *(const bf16x8*)(
            &KsC[row * 64 + (((kd * 2 + hi) + row) & 7) * 8]);
        sf = mfma32(kf, qf[kd], sf);
      }
      __builtin_amdgcn_s_setprio(0);

      // mask -> exp2
      float e[16];
#pragma unroll
      for (int r = 0; r < 16; ++r) {
        float s = sf[r];
        if (diag) {
          const int kc = t * 64 + ms * 32 + (r & 3) + 8 * (r >> 2) + 4 * hi;
          s = (kc <= q0s + l31) ? s : -1e30f;
        }
        e[r] = __builtin_amdgcn_exp2f(s);
      }

      // in-register P: pack bf16 pairs, swap halves across lane<32/lane>=32
      uint32_t W[8];
#pragma unroll
      for (int i = 0; i < 8; ++i) W[i] = pack2(e[2 * i], e[2 * i + 1]);
      uint2v s0 = permswap(W[0], W[2]);
      uint2v s1 = permswap(W[1], W[3]);
      bf16x8 pa = mk_pf(s0.x, s1.x, s0.y, s1.y);
      uint2v s2 = permswap(W[4], W[6]);
      uint2v s3 = permswap(W[5], W[7]);
      bf16x8 pb = mk_pf(s2.x, s3.x, s2.y, s3.y);

      // V(t) staged (drains K(t+1),V(t); leaves K(t+2),V(t+1) in flight)
      asm volatile("s_waitcnt vmcnt(4)" ::: "memory");
      __builtin_amdgcn_sched_barrier(0);

      const bf16* VsC = &Vs[t & 1][0];
      const int ksA = ms * 2, ksB = ms * 2 + 1;
      const int r0 = l31, r1 = 32 + l31;
      bf16x8 va0 = *(const bf16x8*)(&VsC[r0 * 64 + (((ksA * 2 + hi) + r0) & 7) * 8]);
      bf16x8 va1 = *(const bf16x8*)(&VsC[r1 * 64 + (((ksA * 2 + hi) + r1) & 7) * 8]);
      bf16x8 vb0 = *(const bf16x8*)(&VsC[r0 * 64 + (((ksB * 2 + hi) + r0) & 7) * 8]);
      bf16x8 vb1 = *(const bf16x8*)(&VsC[r1 * 64 + (((ksB * 2 + hi) + r1) & 7) * 8]);

      __builtin_amdgcn_s_setprio(1);
      O0 = mfma32(pa, va0, O0);
      O1 = mfma32(pa, va1, O1);
      Ol = mfma32(pa, ones, Ol);
      O0 = mfma32(pb, vb0, O0);
      O1 = mfma32(pb, vb1, O1);
      Ol = mfma32(pb, ones, Ol);
      __builtin_amdgcn_s_setprio(0);
    }
    kr = (kr == 2) ? 0 : kr + 1;
  }

  // merge ms halves (R13-verified layout): full drain once, reuse LDS.
  __syncthreads();
  float* fO = (float*)(&Ks[0][0]);  // [strip][ql][d] = 4096 floats (16KB)
  float* fL = (float*)(&Vs[0][0]);  // [strip][ql] = 64 floats
  if (ms == 1) {
#pragma unroll
    for (int r = 0; r < 16; ++r) {
      const int ql = (r & 3) + 8 * (r >> 2) + 4 * hi;
      fO[strip * 2048 + ql * 64 + l31] = O0[r];
      fO[strip * 2048 + ql * 64 + 32 + l31] = O1[r];
      if (l31 == 0) fL[strip * 32 + ql] = Ol[r];
    }
  }
  __syncthreads();
  if (ms == 0) {
#pragma unroll
    for (int r = 0; r < 16; ++r) {
      const int ql = (r & 3) + 8 * (r >> 2) + 4 * hi;
      const float o0 = O0[r] + fO[strip * 2048 + ql * 64 + l31];
      const float o1 = O1[r] + fO[strip * 2048 + ql * 64 + 32 + l31];
      const float inv = 1.f / (Ol[r] + fL[strip * 32 + ql]);
      bf16* dst = attnb + ((size_t)(b * 2048 + q0s + ql)) * 1024 + h * 64;
      dst[l31] = (bf16)(o0 * inv);
      dst[32 + l31] = (bf16)(o1 * inv);
    }
  }
}

// ---------------------------------------------------------------------------
extern "C" void kernel_launch(void* const* d_in, const int* in_sizes, int n_in,
                              void* d_out, int out_size, void* d_ws, size_t ws_size,
                              hipStream_t stream) {
  const float* x     = (const float*)d_in[0];  // (2,2048,1024)
  const float* w_qkv = (const float*)d_in[1];  // (1024,3072)
  const float* b_qkv = (const float*)d_in[2];  // (3072)
  const float* w_o   = (const float*)d_in[3];  // (1024,1024)
  const float* b_o   = (const float*)d_in[4];  // (1024)
  float* out = (float*)d_out;                  // (2,2048,1024) fp32

  char* ws = (char*)d_ws;
  bf16* xb    = (bf16*)ws; ws += (size_t)4096 * 1024 * 2;
  bf16* wqkvt = (bf16*)ws; ws += (size_t)3072 * 1024 * 2;
  bf16* wot   = (bf16*)ws; ws += (size_t)1024 * 1024 * 2;
  bf16* qb    = (bf16*)ws; ws += (size_t)32 * 2048 * 64 * 2;
  bf16* kb    = (bf16*)ws; ws += (size_t)32 * 2048 * 64 * 2;
  bf16* vtb   = (bf16*)ws; ws += (size_t)32 * 2048 * 64 * 2;  // (bh,64,S)
  bf16* attnb = (bf16*)ws; ws += (size_t)4096 * 1024 * 2;

  prep_kernel<<<8192, 256, 0, stream>>>(x, xb, w_qkv, wqkvt, w_o, wot);
  gemm_bt_kernel<0, 4><<<dim3(24, 32), 256, 0, stream>>>(
      xb, wqkvt, b_qkv, nullptr, qb, kb, vtb, 3072, 1024);
  attn_kernel<<<1024, 256, 0, stream>>>(qb, kb, vtb, attnb);
  gemm_bt_kernel<1, 2><<<dim3(8, 64), 256, 0, stream>>>(
      attnb, wot, b_o, out, nullptr, nullptr, nullptr, 1024, 1024);
}

// Round 13
// 164.491 us; speedup vs baseline: 1.2016x; 1.0150x over previous
//
#include <hip/hip_runtime.h>
#include <stdint.h>

// ---------------------------------------------------------------------------
// MultiheadMaskedAttention (B=2, S=2048, H=1024, 16 heads x d=64)
// R22: R21 + XCD-aware 2D block banding in both GEMMs (T1 adapted).
// Mechanism: gemm staging is latency-bound on the drain tail (R17 PMC:
// MfmaUtil 20/VALU 14/HBM 18%). Default dispatch (round-robin, gridDim.x=24
// = 0 mod 8) makes B-panels XCD-local (L2, ~200cyc) but A-panels L3-wide
// (~600cyc) -> A sets the drain tail. Banding gives each XCD an 8x12
// (gemm1) / 16x4 (gemm2) block region traversed col-major: A-band 2MB +
// live B-panel 0.25MB < 4MB L2 -> both operands stage from L2.
// Bijective: 768=8x96, 512=8x64 (verified); epilogue nn>>10 uniformity
// preserved (n0 stays 128-aligned). attn (R16 counted-vmcnt) and prep
// frozen. BK=64 GEMM structure from R21 (harness-verified).
// ---------------------------------------------------------------------------

typedef __bf16 bf16;
typedef __attribute__((ext_vector_type(8))) __bf16 bf16x8;
typedef __attribute__((ext_vector_type(4))) __bf16 bf16x4;
typedef __attribute__((ext_vector_type(4))) float floatx4;
typedef __attribute__((ext_vector_type(16))) float floatx16;
typedef __attribute__((ext_vector_type(4))) unsigned int uint4v;
typedef __attribute__((ext_vector_type(2))) unsigned int uint2v;

#define SCL 0.18033688011112042f  // (1/sqrt(64)) * log2(e)

__device__ __forceinline__ floatx4 mfma_bf16(bf16x8 a, bf16x8 b, floatx4 c) {
  return __builtin_amdgcn_mfma_f32_16x16x32_bf16(a, b, c, 0, 0, 0);
}

// 32x32x16: A lane l holds m=l&31, k=(l>>5)*8+j ; B: n=l&31, k=(l>>5)*8+j ;
// D: n=lane&31, m=(reg&3)+8*(reg>>2)+4*(lane>>5)  [verified m74/m101, R12]
__device__ __forceinline__ floatx16 mfma32(bf16x8 a, bf16x8 b, floatx16 c) {
  return __builtin_amdgcn_mfma_f32_32x32x16_bf16(a, b, c, 0, 0, 0);
}

__device__ __forceinline__ void cp_g2l_16(const bf16* g, bf16* l) {
  // async global->LDS, 16B/lane; LDS dest = wave-uniform base + lane*16
  __builtin_amdgcn_global_load_lds(
      (const __attribute__((address_space(1))) void*)g,
      (__attribute__((address_space(3))) void*)l, 16, 0, 0);
}

__device__ __forceinline__ floatx16 zero16() {
  floatx16 z;
#pragma unroll
  for (int i = 0; i < 16; ++i) z[i] = 0.f;
  return z;
}

// two f32 -> one u32 of 2 bf16 (compiler emits cvt_pk; don't hand-write, m240)
__device__ __forceinline__ uint32_t pack2(float lo, float hi2) {
  union { bf16 h[2]; uint32_t u; } x;
  x.h[0] = (bf16)lo; x.h[1] = (bf16)hi2;
  return x.u;
}

// new_a = {a_lo, b_lo}, new_b = {a_hi, b_hi} across the lane<32 / lane>=32 halves
__device__ __forceinline__ uint2v permswap(uint32_t a, uint32_t b) {
  return __builtin_amdgcn_permlane32_swap(a, b, false, false);
}

__device__ __forceinline__ bf16x8 mk_pf(uint32_t w0, uint32_t w1, uint32_t w2,
                                        uint32_t w3) {
  union { uint4v u; bf16x8 v; } c;
  c.u = (uint4v){w0, w1, w2, w3};
  return c.v;
}

// ---- merged prep: cast x -> bf16 ; cast+transpose w_qkv, w_o ----
__global__ __launch_bounds__(256) void prep_kernel(
    const float* __restrict__ x, bf16* __restrict__ xb,
    const float* __restrict__ w_qkv, bf16* __restrict__ wqkvt,
    const float* __restrict__ w_o, bf16* __restrict__ wot) {
  const int b = blockIdx.x;
  const int tid = threadIdx.x;
  if (b < 4096) {
    const int i = (b * 256 + tid) * 4;
    floatx4 v = *(const floatx4*)(x + i);
    bf16x4 o;
    o[0] = (bf16)v[0]; o[1] = (bf16)v[1]; o[2] = (bf16)v[2]; o[3] = (bf16)v[3];
    *(bf16x4*)(xb + i) = o;
    return;
  }
  __shared__ float tile[32][33];
  const float* W; bf16* Wt; int K, N, n0, k0;
  if (b < 7168) {
    const int bb = b - 4096;
    W = w_qkv; Wt = wqkvt; K = 1024; N = 3072;
    n0 = (bb % 96) * 32; k0 = (bb / 96) * 32;
  } else {
    const int bb = b - 7168;
    W = w_o; Wt = wot; K = 1024; N = 1024;
    n0 = (bb & 31) * 32; k0 = (bb >> 5) * 32;
  }
  const int tx = tid & 31, ty = tid >> 5;
  for (int i = 0; i < 4; ++i)
    tile[ty + 8 * i][tx] = W[(size_t)(k0 + ty + 8 * i) * N + n0 + tx];
  __syncthreads();
  for (int i = 0; i < 4; ++i)
    Wt[(size_t)(n0 + ty + 8 * i) * K + k0 + tx] = (bf16)tile[tx][ty + 8 * i];
}

// ---- GEMM: C = A(M x K bf16 rm) * Bt(N x K bf16 rm)^T + bias ----
// R21 structure (BK=64, 2 barriers/step, 8-slot staging swizzle) +
// R22 XCD-aware block banding.
template <int MODE, int MI>
__global__ __launch_bounds__(256, 3) void gemm_bt_kernel(
    const bf16* __restrict__ A, const bf16* __restrict__ Bt,
    const float* __restrict__ bias, float* __restrict__ outF,
    bf16* __restrict__ qb, bf16* __restrict__ kb, bf16* __restrict__ vtb,
    int N, int K) {
  constexpr int BM = MI * 32;
  __shared__ bf16 As[BM * 64];   // [BM rows][64 cols], 8-slot swizzled
  __shared__ bf16 Bs[128 * 64];
  const int tid = threadIdx.x;
  const int w = tid >> 6, lane = tid & 63;
  const int l16 = lane & 15, quad = lane >> 4;

  // XCD-aware banding: launch-order f -> xcd=f&7 (round-robin dispatch);
  // each XCD owns an 8x12 (MODE 0, grid 24x32) / 16x4 (MODE 1, grid 8x64)
  // region traversed col-major -> A-band + live B-panel stay L2-resident.
  const int f = blockIdx.y * gridDim.x + blockIdx.x;
  const int xcd = f & 7, ii = f >> 3;
  int bx, by;
  if (MODE == 0) {
    by = (xcd >> 1) * 8 + (ii & 7);
    bx = (xcd & 1) * 12 + (ii >> 3);
  } else {
    by = (xcd >> 1) * 16 + (ii & 15);
    bx = (xcd & 1) * 4 + (ii >> 4);
  }
  const int m0 = by * BM, n0 = bx * 128;
  const int wm = (w & 1) * (BM / 2), wn = (w >> 1) * 64;

  // staging: chunk c (16B): row=c>>3, slot=c&7; LDS dest = c*8 elems
  // (linear); source = logical chunk jj=((c&7)-(c>>3))&7 of that row.
  constexpr int ACH = (BM * 8) / 256;  // 4 (MI=4) or 2 (MI=2)
  const bf16* AgS[ACH];
  const bf16* BgS[4];
#pragma unroll
  for (int p = 0; p < ACH; ++p) {
    const int c = tid + 256 * p;
    AgS[p] = A + (size_t)(m0 + (c >> 3)) * K + ((((c & 7) - (c >> 3)) & 7) * 8);
  }
#pragma unroll
  for (int p = 0; p < 4; ++p) {
    const int c = tid + 256 * p;
    BgS[p] = Bt + (size_t)(n0 + (c >> 3)) * K + ((((c & 7) - (c >> 3)) & 7) * 8);
  }

  floatx4 acc[MI][4];
#pragma unroll
  for (int i = 0; i < MI; ++i)
#pragma unroll
    for (int j = 0; j < 4; ++j) acc[i][j] = (floatx4){0.f, 0.f, 0.f, 0.f};

  for (int k0 = 0; k0 < K; k0 += 64) {  // 16 steps
    __syncthreads();
#pragma unroll
    for (int p = 0; p < ACH; ++p)
      cp_g2l_16(AgS[p] + k0, As + (tid + 256 * p) * 8);
#pragma unroll
    for (int p = 0; p < 4; ++p)
      cp_g2l_16(BgS[p] + k0, Bs + (tid + 256 * p) * 8);
    __syncthreads();

    // fragment reads: row R, logical chunk kq*4+quad -> slot (kq*4+quad+R)&7
    bf16x8 af[MI][2], bfr[4][2];
#pragma unroll
    for (int i = 0; i < MI; ++i) {
      const int R = wm + i * 16 + l16;
#pragma unroll
      for (int kq = 0; kq < 2; ++kq)
        af[i][kq] = *(const bf16x8*)(&As[R * 64 + ((kq * 4 + quad + R) & 7) * 8]);
    }
#pragma unroll
    for (int j = 0; j < 4; ++j) {
      const int Rb = wn + j * 16 + l16;
#pragma unroll
      for (int kq = 0; kq < 2; ++kq)
        bfr[j][kq] = *(const bf16x8*)(&Bs[Rb * 64 + ((kq * 4 + quad + Rb) & 7) * 8]);
    }
#pragma unroll
    for (int i = 0; i < MI; ++i)
#pragma unroll
      for (int j = 0; j < 4; ++j) {
        acc[i][j] = mfma_bf16(af[i][0], bfr[j][0], acc[i][j]);
        acc[i][j] = mfma_bf16(af[i][1], bfr[j][1], acc[i][j]);
      }
  }

#pragma unroll
  for (int i = 0; i < MI; ++i)
#pragma unroll
    for (int j = 0; j < 4; ++j) {
      const int nn = n0 + wn + j * 16 + l16;
      const float bv = bias[nn];
      const int mbase = m0 + wm + i * 16 + quad * 4;
      if (MODE == 1) {
#pragma unroll
        for (int r = 0; r < 4; ++r)
          outF[(size_t)(mbase + r) * N + nn] = acc[i][j][r] + bv;
      } else {
        const int which = nn >> 10;  // uniform per block
        const int rem = nn & 1023;
        const int h = rem >> 6, d = rem & 63;
        const int b = mbase >> 11, s = mbase & 2047;
        const size_t bh = (size_t)(b * 16 + h);
        if (which == 2) {
          bf16x4 pk;
#pragma unroll
          for (int r = 0; r < 4; ++r) pk[r] = (bf16)(acc[i][j][r] + bv);
          *(bf16x4*)(vtb + (bh * 64 + d) * 2048 + s) = pk;
        } else if (which == 0) {
#pragma unroll
          for (int r = 0; r < 4; ++r)
            qb[(bh * 2048 + s + r) * 64 + d] = (bf16)((acc[i][j][r] + bv) * SCL);
        } else {
#pragma unroll
          for (int r = 0; r < 4; ++r)
            kb[(bh * 2048 + s + r) * 64 + d] = (bf16)(acc[i][j][r] + bv);
        }
      }
    }
}

// ---- Flash attention, causal. 1024 blocks x 256 threads (4 waves). ------
// R16 structure (harness-verified): K 3-deep LDS (prefetch distance 2),
// V 2-deep (distance 1); raw s_barrier at loop top; mid-iteration vmcnt(4).
__global__ __launch_bounds__(256, 4) void attn_kernel(
    const bf16* __restrict__ Qb, const bf16* __restrict__ Kb,
    const bf16* __restrict__ Vtb, bf16* __restrict__ attnb) {
  __shared__ bf16 Ks[3][4096];  // [buf][64 s-rows x 64 d] swizzled chunks
  __shared__ bf16 Vs[2][4096];  // [buf][64 d-rows x 64 s] swizzled chunks
  const int bid = blockIdx.x;
  const int c = bid & 255, qq = bid >> 8;
  const int bh = c & 31;        // head: all 32 blocks of a head on one XCD
  const int kk = c >> 5;        // 0..7
  // stride-256 columns get groups {k, 31-k, 8+k, 23-k}: 66 iters/column
  const int g = (qq == 0) ? kk : (qq == 1) ? 31 - kk
              : (qq == 2) ? 8 + kk : 23 - kk;
  const int tid = threadIdx.x;
  const int w = tid >> 6, lane = tid & 63;
  const int l31 = lane & 31, hi = lane >> 5;
  const int strip = w >> 1, ms = w & 1;
  const int q0s = g * 64 + strip * 32;  // this wave's 32 q-rows
  const int b = bh >> 4, h = bh & 15;
  const int nt = g + 1;

  const bf16* Qh = Qb + (size_t)bh * 2048 * 64;
  const bf16* Kh = Kb + (size_t)bh * 2048 * 64;
  const bf16* Vh = Vtb + (size_t)bh * 64 * 2048;

  // staging: thread stages chunks {tid, tid+256} of K and of V (16B each).
  // dest chunk c: row=c>>3, slot=c&7 holds source chunk (slot-row)&7
  const int c0 = tid, c1 = tid + 256;
  const int kof0 = (c0 >> 3) * 64 + ((((c0 & 7) - (c0 >> 3)) & 7) * 8);
  const int kof1 = (c1 >> 3) * 64 + ((((c1 & 7) - (c1 >> 3)) & 7) * 8);
  const int vof0 = (c0 >> 3) * 2048 + ((((c0 & 7) - (c0 >> 3)) & 7) * 8);
  const int vof1 = (c1 >> 3) * 2048 + ((((c1 & 7) - (c1 >> 3)) & 7) * 8);

  // Q B-frags: n=q=q0s+l31, k=d=kd*16+hi*8+j
  bf16x8 qf[4];
  {
    const bf16* Qr = Qh + (size_t)(q0s + l31) * 64 + hi * 8;
#pragma unroll
    for (int kd = 0; kd < 4; ++kd) qf[kd] = *(const bf16x8*)(Qr + kd * 16);
  }
  bf16x8 ones;
#pragma unroll
  for (int j = 0; j < 8; ++j) ones[j] = (bf16)1.0f;

  floatx16 O0 = zero16(), O1 = zero16(), Ol = zero16();

  // prologue: K(0)->Kb0, K(1 or clamp)->Kb1, V(0)->Vb0 ; keep K1,V0 in flight
  {
    const int k1 = (1 < nt) ? 1 : 0;
    cp_g2l_16(Kh + kof0, &Ks[0][c0 * 8]);
    cp_g2l_16(Kh + kof1, &Ks[0][c1 * 8]);
    cp_g2l_16(Kh + (size_t)k1 * 4096 + kof0, &Ks[1][c0 * 8]);
    cp_g2l_16(Kh + (size_t)k1 * 4096 + kof1, &Ks[1][c1 * 8]);
    cp_g2l_16(Vh + vof0, &Vs[0][c0 * 8]);
    cp_g2l_16(Vh + vof1, &Vs[0][c1 * 8]);
    asm volatile("s_waitcnt vmcnt(4)" ::: "memory");  // K(0) staged
    __builtin_amdgcn_sched_barrier(0);
  }

  int kr = 0;  // K read buffer = t % 3
  for (int t = 0; t < nt; ++t) {
    // all waves: K(t) visible (issuer drained at its mid-(t-1) vmcnt(4));
    // buffers being overwritten below were fully read during t-1.
    __builtin_amdgcn_s_barrier();
    __builtin_amdgcn_sched_barrier(0);

    // issue staging: K(t+2)->Kb[(t+2)%3], V(t+1)->Vb[(t+1)&1].
    // Tail: clamped source (tile 0) into the (dead) dest keeps vmcnt uniform.
    {
      const int tk = (t + 2 < nt) ? t + 2 : 0;
      const int tv = (t + 1 < nt) ? t + 1 : 0;
      const int kst = (kr >= 1) ? kr - 1 : 2;  // (t+2)%3
      cp_g2l_16(Kh + (size_t)tk * 4096 + kof0, &Ks[kst][c0 * 8]);
      cp_g2l_16(Kh + (size_t)tk * 4096 + kof1, &Ks[kst][c1 * 8]);
      cp_g2l_16(Vh + (size_t)tv * 64 + vof0, &Vs[(t + 1) & 1][c0 * 8]);
      cp_g2l_16(Vh + (size_t)tv * 64 + vof1, &Vs[(t + 1) & 1][c1 * 8]);
    }

    const bool diag = (t == g);
    if (!(diag && strip == 0 && ms == 1)) {  // skip fully-masked half-tile
      const bf16* KsC = &Ks[kr][0];

      // S^T = K*Q^T over this wave's 32 s-rows: 4 chained MFMAs over d
      floatx16 sf = zero16();
      const int row = ms * 32 + l31;
      __builtin_amdgcn_s_setprio(1);
#pragma unroll
      for (int kd = 0; kd < 4; ++kd) {
        bf16x8 kf = *(const bf16x8*)(
            &KsC[row * 64 + (((kd * 2 + hi) + row) & 7) * 8]);
        sf = mfma32(kf, qf[kd], sf);
      }
      __builtin_amdgcn_s_setprio(0);

      // mask -> exp2
      float e[16];
#pragma unroll
      for (int r = 0; r < 16; ++r) {
        float s = sf[r];
        if (diag) {
          const int kc = t * 64 + ms * 32 + (r & 3) + 8 * (r >> 2) + 4 * hi;
          s = (kc <= q0s + l31) ? s : -1e30f;
        }
        e[r] = __builtin_amdgcn_exp2f(s);
      }

      // in-register P: pack bf16 pairs, swap halves across lane<32/lane>=32
      uint32_t W[8];
#pragma unroll
      for (int i = 0; i < 8; ++i) W[i] = pack2(e[2 * i], e[2 * i + 1]);
      uint2v s0 = permswap(W[0], W[2]);
      uint2v s1 = permswap(W[1], W[3]);
      bf16x8 pa = mk_pf(s0.x, s1.x, s0.y, s1.y);
      uint2v s2 = permswap(W[4], W[6]);
      uint2v s3 = permswap(W[5], W[7]);
      bf16x8 pb = mk_pf(s2.x, s3.x, s2.y, s3.y);

      // V(t) staged (drains K(t+1),V(t); leaves K(t+2),V(t+1) in flight)
      asm volatile("s_waitcnt vmcnt(4)" ::: "memory");
      __builtin_amdgcn_sched_barrier(0);

      const bf16* VsC = &Vs[t & 1][0];
      const int ksA = ms * 2, ksB = ms * 2 + 1;
      const int r0 = l31, r1 = 32 + l31;
      bf16x8 va0 = *(const bf16x8*)(&VsC[r0 * 64 + (((ksA * 2 + hi) + r0) & 7) * 8]);
      bf16x8 va1 = *(const bf16x8*)(&VsC[r1 * 64 + (((ksA * 2 + hi) + r1) & 7) * 8]);
      bf16x8 vb0 = *(const bf16x8*)(&VsC[r0 * 64 + (((ksB * 2 + hi) + r0) & 7) * 8]);
      bf16x8 vb1 = *(const bf16x8*)(&VsC[r1 * 64 + (((ksB * 2 + hi) + r1) & 7) * 8]);

      __builtin_amdgcn_s_setprio(1);
      O0 = mfma32(pa, va0, O0);
      O1 = mfma32(pa, va1, O1);
      Ol = mfma32(pa, ones, Ol);
      O0 = mfma32(pb, vb0, O0);
      O1 = mfma32(pb, vb1, O1);
      Ol = mfma32(pb, ones, Ol);
      __builtin_amdgcn_s_setprio(0);
    }
    kr = (kr == 2) ? 0 : kr + 1;
  }

  // merge ms halves (R13-verified layout): full drain once, reuse LDS.
  __syncthreads();
  float* fO = (float*)(&Ks[0][0]);  // [strip][ql][d] = 4096 floats (16KB)
  float* fL = (float*)(&Vs[0][0]);  // [strip][ql] = 64 floats
  if (ms == 1) {
#pragma unroll
    for (int r = 0; r < 16; ++r) {
      const int ql = (r & 3) + 8 * (r >> 2) + 4 * hi;
      fO[strip * 2048 + ql * 64 + l31] = O0[r];
      fO[strip * 2048 + ql * 64 + 32 + l31] = O1[r];
      if (l31 == 0) fL[strip * 32 + ql] = Ol[r];
    }
  }
  __syncthreads();
  if (ms == 0) {
#pragma unroll
    for (int r = 0; r < 16; ++r) {
      const int ql = (r & 3) + 8 * (r >> 2) + 4 * hi;
      const float o0 = O0[r] + fO[strip * 2048 + ql * 64 + l31];
      const float o1 = O1[r] + fO[strip * 2048 + ql * 64 + 32 + l31];
      const float inv = 1.f / (Ol[r] + fL[strip * 32 + ql]);
      bf16* dst = attnb + ((size_t)(b * 2048 + q0s + ql)) * 1024 + h * 64;
      dst[l31] = (bf16)(o0 * inv);
      dst[32 + l31] = (bf16)(o1 * inv);
    }
  }
}

// ---------------------------------------------------------------------------
extern "C" void kernel_launch(void* const* d_in, const int* in_sizes, int n_in,
                              void* d_out, int out_size, void* d_ws, size_t ws_size,
                              hipStream_t stream) {
  const float* x     = (const float*)d_in[0];  // (2,2048,1024)
  const float* w_qkv = (const float*)d_in[1];  // (1024,3072)
  const float* b_qkv = (const float*)d_in[2];  // (3072)
  const float* w_o   = (const float*)d_in[3];  // (1024,1024)
  const float* b_o   = (const float*)d_in[4];  // (1024)
  float* out = (float*)d_out;                  // (2,2048,1024) fp32

  char* ws = (char*)d_ws;
  bf16* xb    = (bf16*)ws; ws += (size_t)4096 * 1024 * 2;
  bf16* wqkvt = (bf16*)ws; ws += (size_t)3072 * 1024 * 2;
  bf16* wot   = (bf16*)ws; ws += (size_t)1024 * 1024 * 2;
  bf16* qb    = (bf16*)ws; ws += (size_t)32 * 2048 * 64 * 2;
  bf16* kb    = (bf16*)ws; ws += (size_t)32 * 2048 * 64 * 2;
  bf16* vtb   = (bf16*)ws; ws += (size_t)32 * 2048 * 64 * 2;  // (bh,64,S)
  bf16* attnb = (bf16*)ws; ws += (size_t)4096 * 1024 * 2;

  prep_kernel<<<8192, 256, 0, stream>>>(x, xb, w_qkv, wqkvt, w_o, wot);
  gemm_bt_kernel<0, 4><<<dim3(24, 32), 256, 0, stream>>>(
      xb, wqkvt, b_qkv, nullptr, qb, kb, vtb, 3072, 1024);
  attn_kernel<<<1024, 256, 0, stream>>>(qb, kb, vtb, attnb);
  gemm_bt_kernel<1, 2><<<dim3(8, 64), 256, 0, stream>>>(
      attnb, wot, b_o, out, nullptr, nullptr, nullptr, 1024, 1024);
}